// Round 1
// baseline (1361.403 us; speedup 1.0000x reference)
//
#include <hip/hip_runtime.h>
#include <math.h>

#define T_DIM 2048
#define C_DIM 1024
#define B_DIM 8
#define TB    32
#define SMAX  288          // TB + 2*128
#define NEGE  -1.0e30f

// Block: 256 threads = 8 groups (ig) x 32 lanes (j).
// Phase 1: E[32][288] = Q_tile @ K_band^T (E in regs, 4x9 per thread)
// Phase 2: exact softmax per t-row -> P in LDS
// Phase 3: O = P @ V_band, c-chunks of 256, then masked row-max
__global__ __launch_bounds__(256, 2)
void attn_band_kernel(const float* __restrict__ Q, const float* __restrict__ K,
                      const float* __restrict__ V, const float* __restrict__ Mask,
                      const int* __restrict__ m_ptr, float* __restrict__ ws)
{
    const int b   = blockIdx.y;
    const int t0  = blockIdx.x * TB;
    const int tid = threadIdx.x;
    const int ig  = tid >> 5;   // 0..7
    const int j   = tid & 31;   // 0..31
    const int m   = m_ptr[0];   // 128 in this instance

    const int s_lo = max(0, t0 - m);
    const int s_hi = min(T_DIM - 1, t0 + TB - 1 + m);

    // LDS: phase1 {Qc[32][64], Kc[96][64]} overlaps phase2/3 {P[32][288]}; Vc separate
    __shared__ float sm[TB * SMAX + 16 * 256];  // 13312 floats = 53 KB
    float* Pl = sm;                  // [32][288]
    float* Vc = sm + TB * SMAX;      // [16][256]
    float* Qc = sm;                  // [32][64] (f4-swizzled)
    float* Kc = sm + TB * 64;        // [96][64] (f4-swizzled)

    const float* Qb = Q + (size_t)b * T_DIM * C_DIM;
    const float* Kb = K + (size_t)b * T_DIM * C_DIM;
    const float* Vb = V + (size_t)b * T_DIM * C_DIM;

    // ---------------- Phase 1: banded QK^T ----------------
    float E[4][9];
#pragma unroll
    for (int r = 0; r < 4; ++r)
#pragma unroll
        for (int k = 0; k < 9; ++k) E[r][k] = 0.f;

#pragma unroll
    for (int st = 0; st < 3; ++st) {
        const int sbase = s_lo + st * 96;
        if (sbase <= s_hi) {
            for (int cc = 0; cc < C_DIM; cc += 64) {
                __syncthreads();
                // stage Q[32][64] as float4, XOR-swizzled within row
                for (int u = tid; u < TB * 16; u += 256) {
                    const int row = u >> 4, c4 = u & 15;
                    float4 val = ((const float4*)(Qb + (size_t)(t0 + row) * C_DIM + cc))[c4];
                    ((float4*)Qc)[row * 16 + (c4 ^ (row & 15))] = val;
                }
                // stage K[96][64] (clamped rows), XOR-swizzled
                for (int u = tid; u < 96 * 16; u += 256) {
                    const int row = u >> 4, c4 = u & 15;
                    const int sg = min(sbase + row, T_DIM - 1);
                    float4 val = ((const float4*)(Kb + (size_t)sg * C_DIM + cc))[c4];
                    ((float4*)Kc)[row * 16 + (c4 ^ (row & 15))] = val;
                }
                __syncthreads();
#pragma unroll
                for (int c4 = 0; c4 < 16; ++c4) {
                    float4 qv[4], kv[3];
#pragma unroll
                    for (int r = 0; r < 4; ++r) {
                        const int row = ig + 8 * r;
                        qv[r] = ((const float4*)Qc)[row * 16 + (c4 ^ (row & 15))];
                    }
#pragma unroll
                    for (int kk = 0; kk < 3; ++kk) {
                        const int row = j + 32 * kk;
                        kv[kk] = ((const float4*)Kc)[row * 16 + (c4 ^ (row & 15))];
                    }
#pragma unroll
                    for (int r = 0; r < 4; ++r)
#pragma unroll
                        for (int kk = 0; kk < 3; ++kk) {
                            E[r][st * 3 + kk] += qv[r].x * kv[kk].x + qv[r].y * kv[kk].y
                                               + qv[r].z * kv[kk].z + qv[r].w * kv[kk].w;
                        }
                }
            }
        }
    }
    __syncthreads();   // phase-1 LDS reads done before P overwrites that region

    // ---------------- Phase 2: softmax -> P ----------------
    const float scale = 0.03125f;   // 1/sqrt(1024)
#pragma unroll
    for (int r = 0; r < 4; ++r) {
        const int tl = ig + 8 * r;
        const int tg = t0 + tl;
        float e[9];
        float mx = -INFINITY;
#pragma unroll
        for (int k = 0; k < 9; ++k) {
            const int sg = s_lo + j + 32 * k;
            int d = tg - sg; if (d < 0) d = -d;
            const bool valid = (sg <= s_hi) && (d <= m);
            e[k] = valid ? E[r][k] * scale : NEGE;
            mx = fmaxf(mx, e[k]);
        }
#pragma unroll
        for (int dd = 16; dd > 0; dd >>= 1) mx = fmaxf(mx, __shfl_xor(mx, dd));
        float sum = 0.f;
#pragma unroll
        for (int k = 0; k < 9; ++k) { e[k] = __expf(e[k] - mx); sum += e[k]; }
#pragma unroll
        for (int dd = 16; dd > 0; dd >>= 1) sum += __shfl_xor(sum, dd);
        const float inv = 1.0f / sum;
#pragma unroll
        for (int k = 0; k < 9; ++k) Pl[tl * SMAX + j + 32 * k] = e[k] * inv;
    }

    // ---------------- Phase 3: O = P @ V, masked row-max ----------------
    float maskv[4], rmax[4];
#pragma unroll
    for (int r = 0; r < 4; ++r) {
        maskv[r] = Mask[(size_t)b * T_DIM + t0 + ig + 8 * r];
        rmax[r]  = -INFINITY;
    }

    for (int cc0 = 0; cc0 < C_DIM; cc0 += 256) {
        float O[4][2][4];
#pragma unroll
        for (int r = 0; r < 4; ++r)
#pragma unroll
            for (int u = 0; u < 2; ++u)
#pragma unroll
                for (int w = 0; w < 4; ++w) O[r][u][w] = 0.f;

        for (int st = 0; st < 18; ++st) {
            const int sbase = s_lo + st * 16;
            if (sbase > s_hi) break;          // block-uniform
            __syncthreads();
            for (int u = tid; u < 16 * 64; u += 256) {
                const int row = u >> 6, c4 = u & 63;
                const int sg = min(sbase + row, T_DIM - 1);
                ((float4*)Vc)[u] = ((const float4*)(Vb + (size_t)sg * C_DIM + cc0))[c4];
            }
            __syncthreads();
#pragma unroll 4
            for (int s = 0; s < 16; ++s) {
                const int sl = st * 16 + s;   // p==0 beyond band, so garbage V is harmless
                float pv[4];
#pragma unroll
                for (int r = 0; r < 4; ++r) pv[r] = Pl[(ig + 8 * r) * SMAX + sl];
                const float4 v0 = ((const float4*)Vc)[s * 64 + j];        // c = cc0 + 4j..
                const float4 v1 = ((const float4*)Vc)[s * 64 + 32 + j];   // c = cc0 + 128 + 4j..
#pragma unroll
                for (int r = 0; r < 4; ++r) {
                    O[r][0][0] += pv[r] * v0.x;  O[r][0][1] += pv[r] * v0.y;
                    O[r][0][2] += pv[r] * v0.z;  O[r][0][3] += pv[r] * v0.w;
                    O[r][1][0] += pv[r] * v1.x;  O[r][1][1] += pv[r] * v1.y;
                    O[r][1][2] += pv[r] * v1.z;  O[r][1][3] += pv[r] * v1.w;
                }
            }
        }
        // fold masked max over this c-chunk
#pragma unroll
        for (int r = 0; r < 4; ++r)
#pragma unroll
            for (int u = 0; u < 2; ++u)
#pragma unroll
                for (int w = 0; w < 4; ++w)
                    rmax[r] = fmaxf(rmax[r], O[r][u][w] * maskv[r]);
    }

    // ---------------- Phase 4: row-max across lanes -> ws ----------------
#pragma unroll
    for (int r = 0; r < 4; ++r) {
        float v = rmax[r];
#pragma unroll
        for (int dd = 16; dd > 0; dd >>= 1) v = fmaxf(v, __shfl_xor(v, dd));
        if (j == 0) ws[(size_t)b * T_DIM + t0 + ig + 8 * r] = v;
    }
}

// out[b] = sum_t ws[b][t]  (deterministic block reduction)
__global__ void reduce_b(const float* __restrict__ ws, float* __restrict__ out)
{
    const int b = blockIdx.x;
    float s = 0.f;
    for (int t = threadIdx.x; t < T_DIM; t += 256) s += ws[(size_t)b * T_DIM + t];
#pragma unroll
    for (int dd = 32; dd > 0; dd >>= 1) s += __shfl_xor(s, dd);
    __shared__ float acc[4];
    if ((threadIdx.x & 63) == 0) acc[threadIdx.x >> 6] = s;
    __syncthreads();
    if (threadIdx.x == 0) out[b] = acc[0] + acc[1] + acc[2] + acc[3];
}

extern "C" void kernel_launch(void* const* d_in, const int* in_sizes, int n_in,
                              void* d_out, int out_size, void* d_ws, size_t ws_size,
                              hipStream_t stream)
{
    const float* Q    = (const float*)d_in[0];
    const float* K    = (const float*)d_in[1];
    const float* V    = (const float*)d_in[2];
    const float* Mask = (const float*)d_in[3];
    const int*   m    = (const int*)d_in[4];
    float* out = (float*)d_out;
    float* ws  = (float*)d_ws;

    attn_band_kernel<<<dim3(T_DIM / TB, B_DIM), 256, 0, stream>>>(Q, K, V, Mask, m, ws);
    reduce_b<<<B_DIM, 256, 0, stream>>>(ws, out);
}

// Round 2
// 142.871 us; speedup vs baseline: 9.5289x; 9.5289x over previous
//
#include <hip/hip_runtime.h>
#include <math.h>

#define T_DIM 2048
#define C_DIM 1024
#define B_DIM 8
#define TB    32
#define SMAX  288
#define BK    64
#define KROW  72      // bf16 elems per Kc/Qc row (64 + 8 pad)
#define PROW  296     // bf16 elems per P / Vt_lds row (288 + 8 pad)
#define NEGE  -1.0e30f

typedef float f32x4 __attribute__((ext_vector_type(4)));
typedef short s16x8 __attribute__((ext_vector_type(8)));

__device__ __forceinline__ unsigned short f2bf(float x) {
    union { float f; unsigned u; } v; v.f = x;
    unsigned r = v.u + 0x7fffu + ((v.u >> 16) & 1u);
    return (unsigned short)(r >> 16);
}
__device__ __forceinline__ unsigned pk2(float a, float b) {
    return (unsigned)f2bf(a) | ((unsigned)f2bf(b) << 16);
}

// ---------------- V transpose: V[b][t][c] f32 -> Vt[b][c][t] bf16 ----------------
__global__ __launch_bounds__(256)
void transpose_v(const float* __restrict__ V, unsigned short* __restrict__ Vt)
{
    __shared__ float buf[64 * 67];   // pad 67: stage2 reads conflict-free
    const int t0 = blockIdx.x * 64;
    const int c0 = blockIdx.y * 64;
    const int b  = blockIdx.z;
    const float* Vb = V + (size_t)b * T_DIM * C_DIM;

    for (int i = threadIdx.x; i < 64 * 64; i += 256) {
        const int r = i >> 6, c = i & 63;
        buf[r * 67 + c] = Vb[(size_t)(t0 + r) * C_DIM + c0 + c];
    }
    __syncthreads();
    const int t8 = threadIdx.x & 7;   // 8-t segment
    const int cl = threadIdx.x >> 3;  // 0..31
#pragma unroll
    for (int half = 0; half < 2; ++half) {
        const int c_loc = cl + half * 32;
        float v[8];
#pragma unroll
        for (int j = 0; j < 8; ++j) v[j] = buf[(t8 * 8 + j) * 67 + c_loc];
        uint4 o;
        o.x = pk2(v[0], v[1]); o.y = pk2(v[2], v[3]);
        o.z = pk2(v[4], v[5]); o.w = pk2(v[6], v[7]);
        *(uint4*)(Vt + (size_t)(b * C_DIM + c0 + c_loc) * T_DIM + t0 + t8 * 8) = o;
    }
}

// ---------------- banded attention, bf16 MFMA ----------------
// 256 thr = 4 waves. wave w: th=w>>1 (t-half of 32-row tile), sh=w&1 (s-half / c-half).
__global__ __launch_bounds__(256, 2)
void attn_band_mfma(const float* __restrict__ Q, const float* __restrict__ K,
                    const unsigned short* __restrict__ Vt,
                    const float* __restrict__ Mask, const int* __restrict__ m_ptr,
                    float* __restrict__ wsrow)
{
    __shared__ __align__(16) char smem_raw[57600];
    short* SM = (short*)smem_raw;
    short* Kc = SM;                    // [288][72] bf16 (phase 1)
    short* Qc = SM + 288 * KROW;       // [32][72]
    short* P  = SM;                    // [32][296] (phase 2/3, aliases Kc)
    short* Vl = SM + 32 * PROW;        // [64][296]
    float* pmax = (float*)(smem_raw + 56832);  // [2][32]
    float* psum = pmax + 64;                   // [2][32]
    float* red  = psum + 64;                   // [2][32]

    // XCD-bijective swizzle: each XCD owns one batch's contiguous t-range
    const int h = blockIdx.x;
    const int logical = (h & 7) * 64 + (h >> 3);
    const int b  = logical >> 6;
    const int t0 = (logical & 63) * TB;

    const int tid = threadIdx.x;
    const int w = tid >> 6, lane = tid & 63, g = lane >> 4, ln = lane & 15;
    const int th = w >> 1, sh = w & 1;
    const int m  = m_ptr[0];

    const int s_lo = max(0, t0 - m);
    const int s_hi = min(T_DIM - 1, t0 + TB - 1 + m);

    const float* Qb = Q + (size_t)b * T_DIM * C_DIM;
    const float* Kb = K + (size_t)b * T_DIM * C_DIM;
    const unsigned short* Vtb = Vt + (size_t)b * C_DIM * T_DIM;

    // ---- phase 1: E[t][s] = Q·K^T over banded s, per wave 16t x 144s ----
    f32x4 E[9];
    f32x4 zed = {0.f, 0.f, 0.f, 0.f};
#pragma unroll
    for (int i = 0; i < 9; ++i) E[i] = zed;

    for (int cc = 0; cc < C_DIM / BK; ++cc) {
        const int c0 = cc * BK;
        __syncthreads();
        for (int u = tid; u < 288 * 8; u += 256) {      // K band rows
            const int su = u >> 3, un = u & 7;
            const int s = min(s_lo + su, T_DIM - 1);
            const float4* src = (const float4*)(Kb + (size_t)s * C_DIM + c0 + un * 8);
            float4 x = src[0], y = src[1];
            uint4 o; o.x = pk2(x.x, x.y); o.y = pk2(x.z, x.w);
            o.z = pk2(y.x, y.y); o.w = pk2(y.z, y.w);
            *(uint4*)(Kc + su * KROW + un * 8) = o;
        }
        {                                                // Q tile: 1 unit/thread
            const int su = tid >> 3, un = tid & 7;
            const float4* src = (const float4*)(Qb + (size_t)(t0 + su) * C_DIM + c0 + un * 8);
            float4 x = src[0], y = src[1];
            uint4 o; o.x = pk2(x.x, x.y); o.y = pk2(x.z, x.w);
            o.z = pk2(y.x, y.y); o.w = pk2(y.z, y.w);
            *(uint4*)(Qc + su * KROW + un * 8) = o;
        }
        __syncthreads();
        s16x8 aq[2];
#pragma unroll
        for (int kk = 0; kk < 2; ++kk)
            aq[kk] = *(const s16x8*)(Qc + (th * 16 + ln) * KROW + kk * 32 + g * 8);
#pragma unroll
        for (int i = 0; i < 9; ++i) {
            const int srow = (sh * 9 + i) * 16 + ln;
#pragma unroll
            for (int kk = 0; kk < 2; ++kk) {
                s16x8 bk = *(const s16x8*)(Kc + srow * KROW + kk * 32 + g * 8);
                E[i] = __builtin_amdgcn_mfma_f32_16x16x32_bf16(aq[kk], bk, E[i], 0, 0, 0);
            }
        }
    }

    // ---- phase 2: exact softmax (cross-wave over the two s-halves) ----
    const float scale = 0.03125f;   // 1/sqrt(1024)
    const int rowb = th * 16 + g * 4;
    float lm[4];
#pragma unroll
    for (int r = 0; r < 4; ++r) lm[r] = -INFINITY;
    const int s_base = s_lo + sh * 144 + ln;
#pragma unroll
    for (int i = 0; i < 9; ++i) {
        const int s = s_base + i * 16;
#pragma unroll
        for (int r = 0; r < 4; ++r) {
            const int t = t0 + rowb + r;
            int d = t - s; d = d < 0 ? -d : d;
            const bool valid = (s <= s_hi) && (d <= m);
            float e = valid ? E[i][r] : -INFINITY;
            E[i][r] = e;
            lm[r] = fmaxf(lm[r], e);
        }
    }
#pragma unroll
    for (int r = 0; r < 4; ++r)
#pragma unroll
        for (int dd = 1; dd < 16; dd <<= 1) lm[r] = fmaxf(lm[r], __shfl_xor(lm[r], dd));
    if (ln == 0) {
#pragma unroll
        for (int r = 0; r < 4; ++r) pmax[sh * 32 + rowb + r] = lm[r];
    }
    __syncthreads();
    float Mr[4], sum[4];
#pragma unroll
    for (int r = 0; r < 4; ++r) {
        Mr[r] = fmaxf(pmax[rowb + r], pmax[32 + rowb + r]) * scale;
        sum[r] = 0.f;
    }
#pragma unroll
    for (int i = 0; i < 9; ++i)
#pragma unroll
        for (int r = 0; r < 4; ++r) {
            float e = __expf(E[i][r] * scale - Mr[r]);   // -inf -> 0 exactly
            E[i][r] = e;
            sum[r] += e;
        }
#pragma unroll
    for (int r = 0; r < 4; ++r)
#pragma unroll
        for (int dd = 1; dd < 16; dd <<= 1) sum[r] += __shfl_xor(sum[r], dd);
    if (ln == 0) {
#pragma unroll
        for (int r = 0; r < 4; ++r) psum[sh * 32 + rowb + r] = sum[r];
    }
    __syncthreads();
    float inv[4];
#pragma unroll
    for (int r = 0; r < 4; ++r) inv[r] = 1.0f / (psum[rowb + r] + psum[32 + rowb + r]);
#pragma unroll
    for (int i = 0; i < 9; ++i) {
        const int col = sh * 144 + i * 16 + ln;
#pragma unroll
        for (int r = 0; r < 4; ++r)
            P[(rowb + r) * PROW + col] = (short)f2bf(E[i][r] * inv[r]);
    }
    __syncthreads();

    // ---- phase 3: O = P @ V via Vt (bf16), fold masked row-max ----
    s16x8 pa[9];
#pragma unroll
    for (int kg = 0; kg < 9; ++kg)
        pa[kg] = *(const s16x8*)(P + (th * 16 + ln) * PROW + kg * 32 + g * 8);

    float maskv[4], rmax[4];
#pragma unroll
    for (int r = 0; r < 4; ++r) {
        maskv[r] = Mask[(size_t)b * T_DIM + t0 + rowb + r];
        rmax[r]  = -INFINITY;
    }

    for (int cc = 0; cc < C_DIM / 64; ++cc) {
        __syncthreads();
        for (int i2 = tid; i2 < 64 * 36; i2 += 256) {   // stage Vt chunk [64c][288s]
            const int cr = i2 / 36, un = i2 - cr * 36;
            const int sb = min(s_lo + un * 8, T_DIM - 8);
            uint4 x = *(const uint4*)(Vtb + (size_t)(cc * 64 + cr) * T_DIM + sb);
            *(uint4*)(Vl + cr * PROW + un * 8) = x;
        }
        __syncthreads();
#pragma unroll
        for (int nbi = 0; nbi < 2; ++nbi) {
            const int crow = sh * 32 + nbi * 16 + ln;
            f32x4 O = zed;
#pragma unroll
            for (int kg = 0; kg < 9; ++kg) {
                s16x8 bv = *(const s16x8*)(Vl + crow * PROW + kg * 32 + g * 8);
                O = __builtin_amdgcn_mfma_f32_16x16x32_bf16(pa[kg], bv, O, 0, 0, 0);
            }
#pragma unroll
            for (int r = 0; r < 4; ++r)
                rmax[r] = fmaxf(rmax[r], O[r] * maskv[r]);
        }
    }
#pragma unroll
    for (int r = 0; r < 4; ++r)
#pragma unroll
        for (int dd = 1; dd < 16; dd <<= 1) rmax[r] = fmaxf(rmax[r], __shfl_xor(rmax[r], dd));
    if (ln == 0) {
#pragma unroll
        for (int r = 0; r < 4; ++r) red[sh * 32 + rowb + r] = rmax[r];
    }
    __syncthreads();
    if (tid < 32)
        wsrow[(size_t)b * T_DIM + t0 + tid] = fmaxf(red[tid], red[32 + tid]);
}

// ---------------- fallback: round-0 verified f32 kernel ----------------
__global__ __launch_bounds__(256, 2)
void attn_band_fb(const float* __restrict__ Q, const float* __restrict__ K,
                  const float* __restrict__ V, const float* __restrict__ Mask,
                  const int* __restrict__ m_ptr, float* __restrict__ ws)
{
    const int b   = blockIdx.y;
    const int t0  = blockIdx.x * TB;
    const int tid = threadIdx.x;
    const int ig  = tid >> 5;
    const int j   = tid & 31;
    const int m   = m_ptr[0];

    const int s_lo = max(0, t0 - m);
    const int s_hi = min(T_DIM - 1, t0 + TB - 1 + m);

    __shared__ float sm[TB * SMAX + 16 * 256];
    float* Pl = sm;
    float* Vc = sm + TB * SMAX;
    float* Qc = sm;
    float* Kc = sm + TB * 64;

    const float* Qb = Q + (size_t)b * T_DIM * C_DIM;
    const float* Kb = K + (size_t)b * T_DIM * C_DIM;
    const float* Vb = V + (size_t)b * T_DIM * C_DIM;

    float E[4][9];
#pragma unroll
    for (int r = 0; r < 4; ++r)
#pragma unroll
        for (int k = 0; k < 9; ++k) E[r][k] = 0.f;

#pragma unroll
    for (int st = 0; st < 3; ++st) {
        const int sbase = s_lo + st * 96;
        if (sbase <= s_hi) {
            for (int cc = 0; cc < C_DIM; cc += 64) {
                __syncthreads();
                for (int u = tid; u < TB * 16; u += 256) {
                    const int row = u >> 4, c4 = u & 15;
                    float4 val = ((const float4*)(Qb + (size_t)(t0 + row) * C_DIM + cc))[c4];
                    ((float4*)Qc)[row * 16 + (c4 ^ (row & 15))] = val;
                }
                for (int u = tid; u < 96 * 16; u += 256) {
                    const int row = u >> 4, c4 = u & 15;
                    const int sg = min(sbase + row, T_DIM - 1);
                    float4 val = ((const float4*)(Kb + (size_t)sg * C_DIM + cc))[c4];
                    ((float4*)Kc)[row * 16 + (c4 ^ (row & 15))] = val;
                }
                __syncthreads();
#pragma unroll
                for (int c4 = 0; c4 < 16; ++c4) {
                    float4 qv[4], kv[3];
#pragma unroll
                    for (int r = 0; r < 4; ++r) {
                        const int row = ig + 8 * r;
                        qv[r] = ((const float4*)Qc)[row * 16 + (c4 ^ (row & 15))];
                    }
#pragma unroll
                    for (int kk = 0; kk < 3; ++kk) {
                        const int row = j + 32 * kk;
                        kv[kk] = ((const float4*)Kc)[row * 16 + (c4 ^ (row & 15))];
                    }
#pragma unroll
                    for (int r = 0; r < 4; ++r)
#pragma unroll
                        for (int kk = 0; kk < 3; ++kk)
                            E[r][st * 3 + kk] += qv[r].x * kv[kk].x + qv[r].y * kv[kk].y
                                               + qv[r].z * kv[kk].z + qv[r].w * kv[kk].w;
                }
            }
        }
    }
    __syncthreads();

    const float scale = 0.03125f;
#pragma unroll
    for (int r = 0; r < 4; ++r) {
        const int tl = ig + 8 * r;
        const int tg = t0 + tl;
        float e[9];
        float mx = -INFINITY;
#pragma unroll
        for (int k = 0; k < 9; ++k) {
            const int sg = s_lo + j + 32 * k;
            int d = tg - sg; if (d < 0) d = -d;
            const bool valid = (sg <= s_hi) && (d <= m);
            e[k] = valid ? E[r][k] * scale : NEGE;
            mx = fmaxf(mx, e[k]);
        }
#pragma unroll
        for (int dd = 16; dd > 0; dd >>= 1) mx = fmaxf(mx, __shfl_xor(mx, dd));
        float sum = 0.f;
#pragma unroll
        for (int k = 0; k < 9; ++k) { e[k] = __expf(e[k] - mx); sum += e[k]; }
#pragma unroll
        for (int dd = 16; dd > 0; dd >>= 1) sum += __shfl_xor(sum, dd);
        const float inv = 1.0f / sum;
#pragma unroll
        for (int k = 0; k < 9; ++k) Pl[tl * SMAX + j + 32 * k] = e[k] * inv;
    }

    float maskv[4], rmax[4];
#pragma unroll
    for (int r = 0; r < 4; ++r) {
        maskv[r] = Mask[(size_t)b * T_DIM + t0 + ig + 8 * r];
        rmax[r]  = -INFINITY;
    }

    for (int cc0 = 0; cc0 < C_DIM; cc0 += 256) {
        float O[4][2][4];
#pragma unroll
        for (int r = 0; r < 4; ++r)
#pragma unroll
            for (int u = 0; u < 2; ++u)
#pragma unroll
                for (int w2 = 0; w2 < 4; ++w2) O[r][u][w2] = 0.f;

        for (int st = 0; st < 18; ++st) {
            const int sbase = s_lo + st * 16;
            if (sbase > s_hi) break;
            __syncthreads();
            for (int u = tid; u < 16 * 64; u += 256) {
                const int row = u >> 6;
                const int sg = min(sbase + row, T_DIM - 1);
                ((float4*)Vc)[u] = ((const float4*)(Vb + (size_t)sg * C_DIM + cc0))[u & 63];
            }
            __syncthreads();
#pragma unroll 4
            for (int s = 0; s < 16; ++s) {
                const int sl = st * 16 + s;
                float pv[4];
#pragma unroll
                for (int r = 0; r < 4; ++r) pv[r] = Pl[(ig + 8 * r) * SMAX + sl];
                const float4 v0 = ((const float4*)Vc)[s * 64 + j];
                const float4 v1 = ((const float4*)Vc)[s * 64 + 32 + j];
#pragma unroll
                for (int r = 0; r < 4; ++r) {
                    O[r][0][0] += pv[r] * v0.x;  O[r][0][1] += pv[r] * v0.y;
                    O[r][0][2] += pv[r] * v0.z;  O[r][0][3] += pv[r] * v0.w;
                    O[r][1][0] += pv[r] * v1.x;  O[r][1][1] += pv[r] * v1.y;
                    O[r][1][2] += pv[r] * v1.z;  O[r][1][3] += pv[r] * v1.w;
                }
            }
        }
#pragma unroll
        for (int r = 0; r < 4; ++r)
#pragma unroll
            for (int u = 0; u < 2; ++u)
#pragma unroll
                for (int w2 = 0; w2 < 4; ++w2)
                    rmax[r] = fmaxf(rmax[r], O[r][u][w2] * maskv[r]);
    }
#pragma unroll
    for (int r = 0; r < 4; ++r) {
        float v = rmax[r];
#pragma unroll
        for (int dd = 16; dd > 0; dd >>= 1) v = fmaxf(v, __shfl_xor(v, dd));
        if (j == 0) ws[(size_t)b * T_DIM + t0 + ig + 8 * r] = v;
    }
}

// out[b] = sum_t ws[b][t]
__global__ void reduce_b(const float* __restrict__ ws, float* __restrict__ out)
{
    const int b = blockIdx.x;
    float s = 0.f;
    for (int t = threadIdx.x; t < T_DIM; t += 256) s += ws[(size_t)b * T_DIM + t];
#pragma unroll
    for (int dd = 32; dd > 0; dd >>= 1) s += __shfl_xor(s, dd);
    __shared__ float acc[4];
    if ((threadIdx.x & 63) == 0) acc[threadIdx.x >> 6] = s;
    __syncthreads();
    if (threadIdx.x == 0) out[b] = acc[0] + acc[1] + acc[2] + acc[3];
}

extern "C" void kernel_launch(void* const* d_in, const int* in_sizes, int n_in,
                              void* d_out, int out_size, void* d_ws, size_t ws_size,
                              hipStream_t stream)
{
    const float* Q    = (const float*)d_in[0];
    const float* K    = (const float*)d_in[1];
    const float* V    = (const float*)d_in[2];
    const float* Mask = (const float*)d_in[3];
    const int*   m    = (const int*)d_in[4];
    float* out = (float*)d_out;

    const size_t vt_bytes = (size_t)B_DIM * C_DIM * T_DIM * 2;     // 33.55 MB
    const size_t need = vt_bytes + (size_t)B_DIM * T_DIM * 4;

    if (ws_size >= need) {
        unsigned short* Vt = (unsigned short*)d_ws;
        float* wsrow = (float*)((char*)d_ws + vt_bytes);
        transpose_v<<<dim3(T_DIM / 64, C_DIM / 64, B_DIM), 256, 0, stream>>>(V, Vt);
        attn_band_mfma<<<dim3((T_DIM / TB) * B_DIM), 256, 0, stream>>>(Q, K, Vt, Mask, m, wsrow);
        reduce_b<<<B_DIM, 256, 0, stream>>>(wsrow, out);
    } else {
        float* wsrow = (float*)d_ws;
        attn_band_fb<<<dim3(T_DIM / TB, B_DIM), 256, 0, stream>>>(Q, K, V, Mask, m, wsrow);
        reduce_b<<<B_DIM, 256, 0, stream>>>(wsrow, out);
    }
}

// Round 3
// 138.899 us; speedup vs baseline: 9.8014x; 1.0286x over previous
//
#include <hip/hip_runtime.h>
#include <math.h>

#define T_DIM 2048
#define C_DIM 1024
#define B_DIM 8
#define TB    32
#define KROW  72      // bf16 elems per Kc/Qc row (64 + 8 pad)  [fallback kernel]
#define PROW  296     // bf16 elems per P row (288 + 8 pad)

typedef float f32x4 __attribute__((ext_vector_type(4)));
typedef short s16x8 __attribute__((ext_vector_type(8)));

__device__ __forceinline__ unsigned short f2bf(float x) {
    union { float f; unsigned u; } v; v.f = x;
    unsigned r = v.u + 0x7fffu + ((v.u >> 16) & 1u);
    return (unsigned short)(r >> 16);
}
__device__ __forceinline__ unsigned pk2(float a, float b) {
    return (unsigned)f2bf(a) | ((unsigned)f2bf(b) << 16);
}

// =================== pre-pass: Q,K,V f32 -> fragment-major bf16 ===================
// Qt/Kt[b][tile(128)][kk(32)][lane(64)][8]:  elem = X[b][tile*16+(l&15)][kk*32+(l>>4)*8+j]
// Vtt [b][ct(64)][sg(64)][lane(64)][8]:      elem = V[b][sg*32+(l>>4)*8+j][ct*16+(l&15)]
// grid (320, B): x<128 -> Q tile x; x<256 -> K tile x-128; else V sg = x-256
__global__ __launch_bounds__(256)
void tile_all(const float* __restrict__ Q, const float* __restrict__ K,
              const float* __restrict__ V, unsigned short* __restrict__ Qt,
              unsigned short* __restrict__ Kt, unsigned short* __restrict__ Vtt)
{
    __shared__ float buf[32 * 265];   // 33,920 B; stride 265 keeps LDS reads ~2-way
    const int bx = blockIdx.x, b = blockIdx.y, tid = threadIdx.x;

    if (bx < 256) {
        const int tile = bx & 127;
        const float* src = (bx < 128) ? Q : K;
        unsigned short* dst = (bx < 128) ? Qt : Kt;
        for (int cc4 = 0; cc4 < 4; ++cc4) {
            __syncthreads();
            for (int u = tid; u < 16 * 64; u += 256) {
                const int row = u >> 6, c4 = u & 63;
                *(float4*)(buf + row * 265 + c4 * 4) =
                    *(const float4*)(src + (size_t)(b * T_DIM + tile * 16 + row) * C_DIM + cc4 * 256 + c4 * 4);
            }
            __syncthreads();
            for (int u = tid; u < 512; u += 256) {
                const int kk_loc = u >> 6, l = u & 63, ln = l & 15, g = l >> 4;
                const float* p = buf + ln * 265 + kk_loc * 32 + g * 8;
                uint4 o; o.x = pk2(p[0], p[1]); o.y = pk2(p[2], p[3]);
                o.z = pk2(p[4], p[5]); o.w = pk2(p[6], p[7]);
                const int kk = cc4 * 8 + kk_loc;
                *(uint4*)(dst + (size_t)(((b * 128 + tile) * 32 + kk) * 64 + l) * 8) = o;
            }
        }
    } else {
        const int sg = bx - 256;   // 0..63
        for (int cc4 = 0; cc4 < 4; ++cc4) {
            __syncthreads();
            for (int u = tid; u < 32 * 64; u += 256) {
                const int row = u >> 6, c4 = u & 63;
                *(float4*)(buf + row * 265 + c4 * 4) =
                    *(const float4*)(V + (size_t)(b * T_DIM + sg * 32 + row) * C_DIM + cc4 * 256 + c4 * 4);
            }
            __syncthreads();
            for (int u = tid; u < 1024; u += 256) {
                const int ct_loc = u >> 6, l = u & 63, ln = l & 15, g = l >> 4;
                float v[8];
#pragma unroll
                for (int j = 0; j < 8; ++j) v[j] = buf[(g * 8 + j) * 265 + ct_loc * 16 + ln];
                uint4 o; o.x = pk2(v[0], v[1]); o.y = pk2(v[2], v[3]);
                o.z = pk2(v[4], v[5]); o.w = pk2(v[6], v[7]);
                const int ct = cc4 * 16 + ct_loc;
                *(uint4*)(Vtt + (size_t)(((b * 64 + ct) * 64 + sg) * 64 + l) * 8) = o;
            }
        }
    }
}

// =================== banded attention: operands direct-from-global ===================
// 256 thr = 4 waves (th = t-half of 32-row tile, sh = s-half / c-split).
// No K/V staging: fragment loads are 1KB coalesced wave loads from Qt/Kt/Vtt.
__global__ __launch_bounds__(256, 2)
void attn_band_tiled(const unsigned short* __restrict__ Qt,
                     const unsigned short* __restrict__ Kt,
                     const unsigned short* __restrict__ Vtt,
                     const float* __restrict__ Mask, const int* __restrict__ m_ptr,
                     float* __restrict__ wsrow)
{
    __shared__ short P[32 * PROW];            // 18,944 B
    __shared__ float pmax[64], psum[64], red[64];

    // XCD-bijective swizzle: each XCD owns one batch's contiguous t-range
    const int h = blockIdx.x;
    const int logical = (h & 7) * 64 + (h >> 3);
    const int b  = logical >> 6;
    const int t0 = (logical & 63) * TB;

    const int tid = threadIdx.x;
    const int w = tid >> 6, lane = tid & 63, g = lane >> 4, ln = lane & 15;
    const int th = w >> 1, sh = w & 1;
    const int m  = m_ptr[0];

    const int s_lo = max(0, t0 - m);
    const int s_hi = min(T_DIM - 1, t0 + TB - 1 + m);
    const int sg0  = s_lo >> 5;               // 32-aligned by construction
    const int tq   = (t0 >> 4) + th;

    const unsigned short* Qtb = Qt + (size_t)b * 128 * 32 * 512;
    const unsigned short* Ktb = Kt + (size_t)b * 128 * 32 * 512;
    const unsigned short* Vtb = Vtt + (size_t)b * 64 * 64 * 512;

    int stg[9];
#pragma unroll
    for (int i = 0; i < 9; ++i) stg[i] = min(sg0 * 2 + sh * 9 + i, 127);

    // ---- phase 1: E = Q.K^T, fragments streamed from global ----
    f32x4 E[9];
    f32x4 zed = {0.f, 0.f, 0.f, 0.f};
#pragma unroll
    for (int i = 0; i < 9; ++i) E[i] = zed;

#pragma unroll 4
    for (int kk = 0; kk < 32; ++kk) {
        s16x8 aq = *(const s16x8*)(Qtb + (size_t)((tq * 32 + kk) * 64 + lane) * 8);
#pragma unroll
        for (int i = 0; i < 9; ++i) {
            s16x8 bk = *(const s16x8*)(Ktb + (size_t)((stg[i] * 32 + kk) * 64 + lane) * 8);
            E[i] = __builtin_amdgcn_mfma_f32_16x16x32_bf16(aq, bk, E[i], 0, 0, 0);
        }
    }

    // ---- phase 2: exact softmax (cross-wave over the two s-halves) ----
    const float scale = 0.03125f;   // 1/sqrt(1024)
    const int rowb = th * 16 + g * 4;
    float lm[4];
#pragma unroll
    for (int r = 0; r < 4; ++r) lm[r] = -INFINITY;
    const int s_base = s_lo + sh * 144 + ln;
#pragma unroll
    for (int i = 0; i < 9; ++i) {
        const int s = s_base + i * 16;
#pragma unroll
        for (int r = 0; r < 4; ++r) {
            const int t = t0 + rowb + r;
            int d = t - s; d = d < 0 ? -d : d;
            const bool valid = (s <= s_hi) && (d <= m);
            float e = valid ? E[i][r] : -INFINITY;
            E[i][r] = e;
            lm[r] = fmaxf(lm[r], e);
        }
    }
#pragma unroll
    for (int r = 0; r < 4; ++r)
#pragma unroll
        for (int dd = 1; dd < 16; dd <<= 1) lm[r] = fmaxf(lm[r], __shfl_xor(lm[r], dd));
    if (ln == 0) {
#pragma unroll
        for (int r = 0; r < 4; ++r) pmax[sh * 32 + rowb + r] = lm[r];
    }
    __syncthreads();
    float Mr[4], sum[4];
#pragma unroll
    for (int r = 0; r < 4; ++r) {
        Mr[r] = fmaxf(pmax[rowb + r], pmax[32 + rowb + r]) * scale;
        sum[r] = 0.f;
    }
#pragma unroll
    for (int i = 0; i < 9; ++i)
#pragma unroll
        for (int r = 0; r < 4; ++r) {
            float e = __expf(E[i][r] * scale - Mr[r]);   // -inf -> 0 exactly
            E[i][r] = e;
            sum[r] += e;
        }
#pragma unroll
    for (int r = 0; r < 4; ++r)
#pragma unroll
        for (int dd = 1; dd < 16; dd <<= 1) sum[r] += __shfl_xor(sum[r], dd);
    if (ln == 0) {
#pragma unroll
        for (int r = 0; r < 4; ++r) psum[sh * 32 + rowb + r] = sum[r];
    }
    __syncthreads();
    float inv[4];
#pragma unroll
    for (int r = 0; r < 4; ++r) inv[r] = 1.0f / (psum[rowb + r] + psum[32 + rowb + r]);
#pragma unroll
    for (int i = 0; i < 9; ++i) {
        const int col = sh * 144 + i * 16 + ln;
#pragma unroll
        for (int r = 0; r < 4; ++r)
            P[(rowb + r) * PROW + col] = (short)f2bf(E[i][r] * inv[r]);
    }
    __syncthreads();

    // ---- phase 3: O = P @ V, V fragments direct from global; fold masked row-max ----
    s16x8 pa[9];
#pragma unroll
    for (int kg = 0; kg < 9; ++kg)
        pa[kg] = *(const s16x8*)(P + (th * 16 + ln) * PROW + kg * 32 + g * 8);

    int sgc[9];
#pragma unroll
    for (int kg = 0; kg < 9; ++kg) sgc[kg] = min(sg0 + kg, 63);

    float maskv[4], rmax[4];
#pragma unroll
    for (int r = 0; r < 4; ++r) {
        maskv[r] = Mask[(size_t)b * T_DIM + t0 + rowb + r];
        rmax[r]  = -INFINITY;
    }

    for (int q = 0; q < 16; ++q) {
        const int ct0 = q * 4 + sh * 2;
        f32x4 O0 = zed, O1 = zed;
#pragma unroll
        for (int kg = 0; kg < 9; ++kg) {
            s16x8 bv0 = *(const s16x8*)(Vtb + (size_t)(((ct0    ) * 64 + sgc[kg]) * 64 + lane) * 8);
            s16x8 bv1 = *(const s16x8*)(Vtb + (size_t)(((ct0 + 1) * 64 + sgc[kg]) * 64 + lane) * 8);
            O0 = __builtin_amdgcn_mfma_f32_16x16x32_bf16(pa[kg], bv0, O0, 0, 0, 0);
            O1 = __builtin_amdgcn_mfma_f32_16x16x32_bf16(pa[kg], bv1, O1, 0, 0, 0);
        }
#pragma unroll
        for (int r = 0; r < 4; ++r) {
            rmax[r] = fmaxf(rmax[r], O0[r] * maskv[r]);
            rmax[r] = fmaxf(rmax[r], O1[r] * maskv[r]);
        }
    }
#pragma unroll
    for (int r = 0; r < 4; ++r)
#pragma unroll
        for (int dd = 1; dd < 16; dd <<= 1) rmax[r] = fmaxf(rmax[r], __shfl_xor(rmax[r], dd));
    if (ln == 0) {
#pragma unroll
        for (int r = 0; r < 4; ++r) red[sh * 32 + rowb + r] = rmax[r];
    }
    __syncthreads();
    if (tid < 32)
        wsrow[(size_t)b * T_DIM + t0 + tid] = fmaxf(red[tid], red[32 + tid]);
}

// =================== fallback path (round-1, verified) ===================
__global__ __launch_bounds__(256)
void transpose_v(const float* __restrict__ V, unsigned short* __restrict__ Vt)
{
    __shared__ float buf[64 * 67];
    const int t0 = blockIdx.x * 64;
    const int c0 = blockIdx.y * 64;
    const int b  = blockIdx.z;
    const float* Vb = V + (size_t)b * T_DIM * C_DIM;

    for (int i = threadIdx.x; i < 64 * 64; i += 256) {
        const int r = i >> 6, c = i & 63;
        buf[r * 67 + c] = Vb[(size_t)(t0 + r) * C_DIM + c0 + c];
    }
    __syncthreads();
    const int t8 = threadIdx.x & 7;
    const int cl = threadIdx.x >> 3;
#pragma unroll
    for (int half = 0; half < 2; ++half) {
        const int c_loc = cl + half * 32;
        float v[8];
#pragma unroll
        for (int j = 0; j < 8; ++j) v[j] = buf[(t8 * 8 + j) * 67 + c_loc];
        uint4 o;
        o.x = pk2(v[0], v[1]); o.y = pk2(v[2], v[3]);
        o.z = pk2(v[4], v[5]); o.w = pk2(v[6], v[7]);
        *(uint4*)(Vt + (size_t)(b * C_DIM + c0 + c_loc) * T_DIM + t0 + t8 * 8) = o;
    }
}

__global__ __launch_bounds__(256, 2)
void attn_band_mfma(const float* __restrict__ Q, const float* __restrict__ K,
                    const unsigned short* __restrict__ Vt,
                    const float* __restrict__ Mask, const int* __restrict__ m_ptr,
                    float* __restrict__ wsrow)
{
    __shared__ __align__(16) char smem_raw[57600];
    short* SM = (short*)smem_raw;
    short* Kc = SM;
    short* Qc = SM + 288 * KROW;
    short* P  = SM;
    short* Vl = SM + 32 * PROW;
    float* pmax = (float*)(smem_raw + 56832);
    float* psum = pmax + 64;
    float* red  = psum + 64;

    const int h = blockIdx.x;
    const int logical = (h & 7) * 64 + (h >> 3);
    const int b  = logical >> 6;
    const int t0 = (logical & 63) * TB;

    const int tid = threadIdx.x;
    const int w = tid >> 6, lane = tid & 63, g = lane >> 4, ln = lane & 15;
    const int th = w >> 1, sh = w & 1;
    const int m  = m_ptr[0];

    const int s_lo = max(0, t0 - m);
    const int s_hi = min(T_DIM - 1, t0 + TB - 1 + m);

    const float* Qb = Q + (size_t)b * T_DIM * C_DIM;
    const float* Kb = K + (size_t)b * T_DIM * C_DIM;
    const unsigned short* Vtb = Vt + (size_t)b * C_DIM * T_DIM;

    f32x4 E[9];
    f32x4 zed = {0.f, 0.f, 0.f, 0.f};
#pragma unroll
    for (int i = 0; i < 9; ++i) E[i] = zed;

    for (int cc = 0; cc < C_DIM / 64; ++cc) {
        const int c0 = cc * 64;
        __syncthreads();
        for (int u = tid; u < 288 * 8; u += 256) {
            const int su = u >> 3, un = u & 7;
            const int s = min(s_lo + su, T_DIM - 1);
            const float4* src = (const float4*)(Kb + (size_t)s * C_DIM + c0 + un * 8);
            float4 x = src[0], y = src[1];
            uint4 o; o.x = pk2(x.x, x.y); o.y = pk2(x.z, x.w);
            o.z = pk2(y.x, y.y); o.w = pk2(y.z, y.w);
            *(uint4*)(Kc + su * KROW + un * 8) = o;
        }
        {
            const int su = tid >> 3, un = tid & 7;
            const float4* src = (const float4*)(Qb + (size_t)(t0 + su) * C_DIM + c0 + un * 8);
            float4 x = src[0], y = src[1];
            uint4 o; o.x = pk2(x.x, x.y); o.y = pk2(x.z, x.w);
            o.z = pk2(y.x, y.y); o.w = pk2(y.z, y.w);
            *(uint4*)(Qc + su * KROW + un * 8) = o;
        }
        __syncthreads();
        s16x8 aq[2];
#pragma unroll
        for (int kk = 0; kk < 2; ++kk)
            aq[kk] = *(const s16x8*)(Qc + (th * 16 + ln) * KROW + kk * 32 + g * 8);
#pragma unroll
        for (int i = 0; i < 9; ++i) {
            const int srow = (sh * 9 + i) * 16 + ln;
#pragma unroll
            for (int kk = 0; kk < 2; ++kk) {
                s16x8 bk = *(const s16x8*)(Kc + srow * KROW + kk * 32 + g * 8);
                E[i] = __builtin_amdgcn_mfma_f32_16x16x32_bf16(aq[kk], bk, E[i], 0, 0, 0);
            }
        }
    }

    const float scale = 0.03125f;
    const int rowb = th * 16 + g * 4;
    float lm[4];
#pragma unroll
    for (int r = 0; r < 4; ++r) lm[r] = -INFINITY;
    const int s_base = s_lo + sh * 144 + ln;
#pragma unroll
    for (int i = 0; i < 9; ++i) {
        const int s = s_base + i * 16;
#pragma unroll
        for (int r = 0; r < 4; ++r) {
            const int t = t0 + rowb + r;
            int d = t - s; d = d < 0 ? -d : d;
            const bool valid = (s <= s_hi) && (d <= m);
            float e = valid ? E[i][r] : -INFINITY;
            E[i][r] = e;
            lm[r] = fmaxf(lm[r], e);
        }
    }
#pragma unroll
    for (int r = 0; r < 4; ++r)
#pragma unroll
        for (int dd = 1; dd < 16; dd <<= 1) lm[r] = fmaxf(lm[r], __shfl_xor(lm[r], dd));
    if (ln == 0) {
#pragma unroll
        for (int r = 0; r < 4; ++r) pmax[sh * 32 + rowb + r] = lm[r];
    }
    __syncthreads();
    float Mr[4], sum[4];
#pragma unroll
    for (int r = 0; r < 4; ++r) {
        Mr[r] = fmaxf(pmax[rowb + r], pmax[32 + rowb + r]) * scale;
        sum[r] = 0.f;
    }
#pragma unroll
    for (int i = 0; i < 9; ++i)
#pragma unroll
        for (int r = 0; r < 4; ++r) {
            float e = __expf(E[i][r] * scale - Mr[r]);
            E[i][r] = e;
            sum[r] += e;
        }
#pragma unroll
    for (int r = 0; r < 4; ++r)
#pragma unroll
        for (int dd = 1; dd < 16; dd <<= 1) sum[r] += __shfl_xor(sum[r], dd);
    if (ln == 0) {
#pragma unroll
        for (int r = 0; r < 4; ++r) psum[sh * 32 + rowb + r] = sum[r];
    }
    __syncthreads();
    float inv[4];
#pragma unroll
    for (int r = 0; r < 4; ++r) inv[r] = 1.0f / (psum[rowb + r] + psum[32 + rowb + r]);
#pragma unroll
    for (int i = 0; i < 9; ++i) {
        const int col = sh * 144 + i * 16 + ln;
#pragma unroll
        for (int r = 0; r < 4; ++r)
            P[(rowb + r) * PROW + col] = (short)f2bf(E[i][r] * inv[r]);
    }
    __syncthreads();

    s16x8 pa[9];
#pragma unroll
    for (int kg = 0; kg < 9; ++kg)
        pa[kg] = *(const s16x8*)(P + (th * 16 + ln) * PROW + kg * 32 + g * 8);

    float maskv[4], rmax[4];
#pragma unroll
    for (int r = 0; r < 4; ++r) {
        maskv[r] = Mask[(size_t)b * T_DIM + t0 + rowb + r];
        rmax[r]  = -INFINITY;
    }

    for (int cc = 0; cc < C_DIM / 64; ++cc) {
        __syncthreads();
        for (int i2 = tid; i2 < 64 * 36; i2 += 256) {
            const int cr = i2 / 36, un = i2 - cr * 36;
            const int sb = min(s_lo + un * 8, T_DIM - 8);
            uint4 x = *(const uint4*)(Vtb + (size_t)(cc * 64 + cr) * T_DIM + sb);
            *(uint4*)(Vl + cr * PROW + un * 8) = x;
        }
        __syncthreads();
#pragma unroll
        for (int nbi = 0; nbi < 2; ++nbi) {
            const int crow = sh * 32 + nbi * 16 + ln;
            f32x4 O = zed;
#pragma unroll
            for (int kg = 0; kg < 9; ++kg) {
                s16x8 bv = *(const s16x8*)(Vl + crow * PROW + kg * 32 + g * 8);
                O = __builtin_amdgcn_mfma_f32_16x16x32_bf16(pa[kg], bv, O, 0, 0, 0);
            }
#pragma unroll
            for (int r = 0; r < 4; ++r)
                rmax[r] = fmaxf(rmax[r], O[r] * maskv[r]);
        }
    }
#pragma unroll
    for (int r = 0; r < 4; ++r)
#pragma unroll
        for (int dd = 1; dd < 16; dd <<= 1) rmax[r] = fmaxf(rmax[r], __shfl_xor(rmax[r], dd));
    if (ln == 0) {
#pragma unroll
        for (int r = 0; r < 4; ++r) red[sh * 32 + rowb + r] = rmax[r];
    }
    __syncthreads();
    if (tid < 32)
        wsrow[(size_t)b * T_DIM + t0 + tid] = fmaxf(red[tid], red[32 + tid]);
}

// out[b] = sum_t ws[b][t]
__global__ void reduce_b(const float* __restrict__ ws, float* __restrict__ out)
{
    const int b = blockIdx.x;
    float s = 0.f;
    for (int t = threadIdx.x; t < T_DIM; t += 256) s += ws[(size_t)b * T_DIM + t];
#pragma unroll
    for (int dd = 32; dd > 0; dd >>= 1) s += __shfl_xor(s, dd);
    __shared__ float acc[4];
    if ((threadIdx.x & 63) == 0) acc[threadIdx.x >> 6] = s;
    __syncthreads();
    if (threadIdx.x == 0) out[b] = acc[0] + acc[1] + acc[2] + acc[3];
}

extern "C" void kernel_launch(void* const* d_in, const int* in_sizes, int n_in,
                              void* d_out, int out_size, void* d_ws, size_t ws_size,
                              hipStream_t stream)
{
    const float* Q    = (const float*)d_in[0];
    const float* K    = (const float*)d_in[1];
    const float* V    = (const float*)d_in[2];
    const float* Mask = (const float*)d_in[3];
    const int*   m    = (const int*)d_in[4];
    float* out = (float*)d_out;

    const size_t tile_bytes = (size_t)B_DIM * 128 * 32 * 64 * 8 * 2;   // 33,554,432 per tensor
    const size_t need_new   = 3 * tile_bytes + (size_t)B_DIM * T_DIM * 4;
    const size_t vt_bytes   = (size_t)B_DIM * C_DIM * T_DIM * 2;
    const size_t need_r1    = vt_bytes + (size_t)B_DIM * T_DIM * 4;

    if (ws_size >= need_new) {
        unsigned short* Qt  = (unsigned short*)d_ws;
        unsigned short* Kt  = (unsigned short*)((char*)d_ws + tile_bytes);
        unsigned short* Vtt = (unsigned short*)((char*)d_ws + 2 * tile_bytes);
        float* wsrow = (float*)((char*)d_ws + 3 * tile_bytes);
        tile_all<<<dim3(320, B_DIM), 256, 0, stream>>>(Q, K, V, Qt, Kt, Vtt);
        attn_band_tiled<<<dim3((T_DIM / TB) * B_DIM), 256, 0, stream>>>(Qt, Kt, Vtt, Mask, m, wsrow);
        reduce_b<<<B_DIM, 256, 0, stream>>>(wsrow, out);
    } else {
        unsigned short* Vt = (unsigned short*)d_ws;
        float* wsrow = (float*)((char*)d_ws + vt_bytes);
        transpose_v<<<dim3(T_DIM / 64, C_DIM / 64, B_DIM), 256, 0, stream>>>(V, Vt);
        attn_band_mfma<<<dim3((T_DIM / TB) * B_DIM), 256, 0, stream>>>(Q, K, Vt, Mask, m, wsrow);
        reduce_b<<<B_DIM, 256, 0, stream>>>(wsrow, out);
    }
}